// Round 6
// baseline (3063.376 us; speedup 1.0000x reference)
//
#include <hip/hip_runtime.h>

#define BB 4
#define NPT 16384
#define CIN 128
#define SS 1024
#define NS 32
#define PP 131072   // BB*SS*NS
#define TOPKK 2048

typedef unsigned short u16;
typedef unsigned int u32;
typedef unsigned long long u64;
typedef float v2 __attribute__((ext_vector_type(2)));

// ---------- helpers ----------
__device__ __forceinline__ float bf2f(u32 v){ return __uint_as_float(v << 16); }
__device__ __forceinline__ u16 f2bf(float f){
  u32 u = __float_as_uint(f);
  u32 r = (u + 0x7FFFu + ((u >> 16) & 1u)) >> 16;   // RNE
  return (u16)r;
}
__device__ __forceinline__ u32 keyOf(float m){
  u32 u = __float_as_uint(m);
  return (u & 0x80000000u) ? ~u : (u | 0x80000000u);  // monotone in float order
}

// ---------- ws layout (bytes) — total 78,748,160 (75.1 MB) ----------
#define OFF_NEWXYZ 0ull                 // B*S*3 f32        49152
#define OFF_MARGIN 49152ull             // B*N f32          262144
#define OFF_FGMASK 311296ull            // B*N u32          262144
#define OFF_IDXNB  573440ull            // B*S*NS i32       524288
#define OFF_MSTAT  1097728ull           // 64*2 f32         512
#define OFF_SSA    1098240ull           // 3*256 float2     6144
#define OFF_WT0    1104384ull           // 128*64 f32       32768
#define OFF_WT1    1137152ull           // 160*128 f32      81920
#define OFF_WT2    1219072ull           // 128*128 f32      65536
#define OFF_WT3    1284608ull           // 128*256 f32      131072
#define OFF_MPART  1415680ull           // 64*1024*2 f64    1048576
#define OFF_CPART  2464256ull           // 256*2048*2 f64   8388608
#define OFF_REGB   10852864ull          // y0 (16MB f32) then Y1 (32MB bf16)
#define OFF_REGA   44407296ull          // Xb (34.3MB bf16) then Y2 (32MB bf16)
#define WS_NEED    78748160ull

// ---------- prep: transposed/padded fp32 weights ----------
__global__ void k_prep(const float* __restrict__ w1, const float* __restrict__ w2,
                       const float* __restrict__ w3, const float* __restrict__ fw1,
                       float* __restrict__ wt0, float* __restrict__ wt1,
                       float* __restrict__ wt2, float* __restrict__ wt3){
  int gt = blockIdx.x*blockDim.x + threadIdx.x;
  int gs = gridDim.x*blockDim.x;
  for (int i = gt; i < 128*64;  i += gs){ int k=i>>6, m=i&63;  wt0[i] = fw1[m*128+k]; }
  for (int i = gt; i < 160*128; i += gs){ int k=i>>7, m=i&127; wt1[i] = (k<131)? w1[m*131+k] : 0.f; }
  for (int i = gt; i < 128*128; i += gs){ int k=i>>7, m=i&127; wt2[i] = w2[m*128+k]; }
  for (int i = gt; i < 128*256; i += gs){ int k=i>>8, m=i&255; wt3[i] = w3[m*128+k]; }
}

// ---------- mask-head GEMM: y0[b][64][N] = fw1 @ features, + deterministic stat partials ----------
__global__ __launch_bounds__(256) void k_gemm_mask(const float* __restrict__ Wt,    // [128][64]
                                                   const float* __restrict__ feat,  // [B][128][N] f32
                                                   float* __restrict__ y0,
                                                   double* __restrict__ mpart){     // [64][1024][2]
  __shared__ float As[32][64];
  __shared__ float Bs[32][64];
  int t = threadIdx.x, tx = t & 15, ty = t >> 4;
  int p0 = blockIdx.x * 64; int b = blockIdx.z;
  const float* X = feat + (size_t)b * CIN * NPT;
  float acc[4][4] = {};
  int e = t * 8, ka = e >> 6, ca = e & 63;
  for (int kc = 0; kc < 4; kc++){
    const float* wr = Wt + (size_t)(kc*32 + ka) * 64 + ca;
    float4 w0 = *(const float4*)wr;
    float4 w1v = *(const float4*)(wr + 4);
    const float* br = X + (size_t)(kc*32 + ka) * NPT + p0 + ca;
    float4 b0 = *(const float4*)br;
    float4 b1 = *(const float4*)(br + 4);
    __syncthreads();
    *(float4*)&As[ka][ca] = w0; *(float4*)&As[ka][ca+4] = w1v;
    *(float4*)&Bs[ka][ca] = b0; *(float4*)&Bs[ka][ca+4] = b1;
    __syncthreads();
    #pragma unroll
    for (int k = 0; k < 32; k++){
      float4 a = *(float4*)&As[k][ty*4];
      float4 bq = *(float4*)&Bs[k][tx*4];
      float av[4] = {a.x,a.y,a.z,a.w}; float bw[4] = {bq.x,bq.y,bq.z,bq.w};
      #pragma unroll
      for (int i = 0; i < 4; i++)
        #pragma unroll
        for (int j = 0; j < 4; j++) acc[i][j] = fmaf(av[i], bw[j], acc[i][j]);
    }
  }
  #pragma unroll
  for (int i = 0; i < 4; i++){
    int m = ty*4 + i;
    float4 v = make_float4(acc[i][0], acc[i][1], acc[i][2], acc[i][3]);
    *(float4*)(y0 + ((size_t)(b*64 + m)) * NPT + p0 + tx*4) = v;
  }
  __syncthreads();
  float* red = (float*)As;  // 2048 floats
  #pragma unroll
  for (int i = 0; i < 4; i++){
    float s = 0.f, q = 0.f;
    #pragma unroll
    for (int j = 0; j < 4; j++){ s += acc[i][j]; q += acc[i][j]*acc[i][j]; }
    red[((ty*4+i)*16 + tx)*2] = s; red[((ty*4+i)*16 + tx)*2 + 1] = q;
  }
  __syncthreads();
  if (t < 64){
    double s = 0.0, q = 0.0;
    for (int x = 0; x < 16; x++){ s += red[(t*16+x)*2]; q += red[(t*16+x)*2+1]; }
    int slot = b*256 + blockIdx.x;
    mpart[((size_t)t*1024 + slot)*2] = s;
    mpart[((size_t)t*1024 + slot)*2 + 1] = q;
  }
}

__global__ void k_mask_stats(const double* __restrict__ mpart, float* __restrict__ mstat){ // <<<1,64>>>
  int t = threadIdx.x;
  double s = 0.0, q = 0.0;
  for (int i = 0; i < 1024; i++){ s += mpart[((size_t)t*1024 + i)*2]; q += mpart[((size_t)t*1024 + i)*2+1]; }
  double cnt = 65536.0;
  double mu = s/cnt; double var = q/cnt - mu*mu;
  float muf = (float)mu;
  float rs = 1.0f / sqrtf((float)var + 1e-5f);
  mstat[t*2] = muf; mstat[t*2+1] = rs;
}

// ---------- scores + margin ----------
__global__ __launch_bounds__(256) void k_scores(const float* __restrict__ y0, const float* __restrict__ mstat,
                                                const float* __restrict__ fg1, const float* __restrict__ fb1,
                                                const float* __restrict__ fw2, const float* __restrict__ fbias2,
                                                float* __restrict__ margin, float* __restrict__ out3){
  __shared__ float smu[64], srs[64], sg[64], sb[64], sw[128];
  int t = threadIdx.x; int b = blockIdx.y; int n = blockIdx.x*256 + t;
  if (t < 64){ smu[t] = mstat[t*2]; srs[t] = mstat[t*2+1]; sg[t] = fg1[t]; sb[t] = fb1[t]; }
  if (t < 128) sw[t] = fw2[t];
  __syncthreads();
  float a0 = 0.f, a1 = 0.f;
  const float* yb = y0 + (size_t)b*64*NPT + n;
  for (int o = 0; o < 64; o++){
    float y = yb[(size_t)o * NPT];
    float h = __fmul_rn(__fmul_rn(__fsub_rn(y, smu[o]), srs[o]), sg[o]);
    h = __fadd_rn(h, sb[o]);
    h = fmaxf(h, 0.f);
    a0 = fmaf(sw[o], h, a0);
    a1 = fmaf(sw[64+o], h, a1);
  }
  float s0 = __fadd_rn(a0, fbias2[0]);
  float s1 = __fadd_rn(a1, fbias2[1]);
  out3[(size_t)(b*2)*NPT + n] = s0;
  out3[(size_t)(b*2+1)*NPT + n] = s1;
  float m = fmaxf(s0, s1);
  float e0 = expf(__fsub_rn(s0, m));
  float e1 = expf(__fsub_rn(s1, m));
  float den = __fadd_rn(e0, e1);
  float mg = __fsub_rn(__fdiv_rn(e1, den), __fdiv_rn(e0, den));
  margin[b*NPT + n] = mg;
}

// ---------- top-2048 per batch -> fg mask (radix select + stable index tie-break) ----------
__global__ __launch_bounds__(1024) void k_topk(const float* __restrict__ margin, u32* __restrict__ fgmask){
  int t = threadIdx.x; int b = blockIdx.x;
  const float* mg = margin + b*NPT; u32* fm = fgmask + b*NPT;
  __shared__ int hist[256]; __shared__ int sc[1024];
  __shared__ u32 s_bin; __shared__ int s_need; __shared__ int s_run;
  int need = TOPKK; u32 prefix = 0, kmask = 0;
  for (int r = 0; r < 4; r++){
    int shift = 24 - 8*r;
    if (t < 256) hist[t] = 0;
    __syncthreads();
    for (int j = 0; j < 16; j++){
      u32 key = keyOf(mg[j*1024 + t]);
      if ((key & kmask) == prefix) atomicAdd(&hist[(key >> shift) & 255], 1);
    }
    __syncthreads();
    if (t == 0){
      int cum = 0;
      for (int bin = 255; bin >= 0; bin--){
        int c = hist[bin];
        if (cum + c >= need){ s_bin = (u32)bin; s_need = need - cum; break; }
        cum += c;
      }
    }
    __syncthreads();
    prefix |= s_bin << shift; kmask |= 255u << shift; need = s_need;
    __syncthreads();
  }
  u32 T = prefix;
  if (t == 0) s_run = 0;
  __syncthreads();
  for (int j = 0; j < 16; j++){
    int n = j*1024 + t;
    u32 key = keyOf(mg[n]);
    int eq = (key == T) ? 1 : 0;
    int gt = (key > T) ? 1 : 0;
    sc[t] = eq; __syncthreads();
    for (int off = 1; off < 1024; off <<= 1){
      int v = (t >= off) ? sc[t-off] : 0;
      __syncthreads();
      sc[t] += v;
      __syncthreads();
    }
    int excl = sc[t] - eq;
    int flag = gt | (eq & ((s_run + excl) < need ? 1 : 0));
    fm[n] = (u32)flag;
    __syncthreads();
    if (t == 1023) s_run += sc[1023];
    __syncthreads();
  }
}

// ---------- masked FPS: 8 blocks (b x {fg,bg}), 512 sequential selections ----------
// Reduction = one LDS atomicMax(u64) per lane; key carries iteration prefix so no
// slot resets are needed (stale entries always lose). Two alternating slots + the
// single per-iteration barrier make the broadcast read race-free. Update + local
// argmax fused in one pass; coordinates packed as float2 -> v_pk_*_f32 (exact
// per-op IEEE, contraction off).
__global__ __launch_bounds__(512) void k_fps(const float* __restrict__ xyz, const u32* __restrict__ fgmask,
                                             float* __restrict__ newxyz, float* __restrict__ out0,
                                             float* __restrict__ out2){
  #pragma clang fp contract(off)
  int t = threadIdx.x; int b = blockIdx.x >> 1; int which = blockIdx.x & 1; // 0=fg,1=bg
  const float* xb = xyz + (size_t)b * NPT * 3;
  v2 px[16], py[16], pz[16], mind[16];
  #pragma unroll
  for (int r = 0; r < 16; r++){
    int p0 = (2*r)*512 + t, p1 = (2*r+1)*512 + t;
    px[r].x = xb[p0*3];   px[r].y = xb[p1*3];
    py[r].x = xb[p0*3+1]; py[r].y = xb[p1*3+1];
    pz[r].x = xb[p0*3+2]; pz[r].y = xb[p1*3+2];
    u32 m0 = fgmask[b*NPT + p0], m1 = fgmask[b*NPT + p1];
    bool i0 = which ? (m0 == 0u) : (m0 != 0u);
    bool i1 = which ? (m1 == 0u) : (m1 != 0u);
    mind[r].x = i0 ? 1e10f : -1.0f;
    mind[r].y = i1 ? 1e10f : -1.0f;
  }
  __shared__ u64 sred[2];
  if (t < 2) sred[t] = 0ull;
  __syncthreads();
  // initial local argmax (lowest index wins on ties: ascending visit order, strict >)
  float bv = mind[0].x; int bi = t;
  #pragma unroll
  for (int r = 0; r < 16; r++){
    if (r > 0 && mind[r].x > bv){ bv = mind[r].x; bi = (2*r)*512 + t; }
    if (mind[r].y > bv){ bv = mind[r].y; bi = (2*r+1)*512 + t; }
  }
  for (int it = 0; it < 512; it++){
    u64 key = ((u64)(it+1) << 46) | ((u64)keyOf(bv) << 14) | (u64)(16383 - bi);
    atomicMax(&sred[it & 1], key);
    __syncthreads();
    u64 k0 = sred[it & 1];
    int sel = 16383 - (int)(k0 & 0x3FFFu);
    // uniform broadcast load of winner coords (L2-resident)
    float xs = xb[sel*3], ys = xb[sel*3+1], zs = xb[sel*3+2];
    if (t == 0){
      int s = which*512 + it;
      out2[b*1024 + s] = (float)sel;
      newxyz[(b*1024 + s)*3]   = xs;
      newxyz[(b*1024 + s)*3+1] = ys;
      newxyz[(b*1024 + s)*3+2] = zs;
      out0[(b*1024 + s)*3]   = xs;
      out0[(b*1024 + s)*3+1] = ys;
      out0[(b*1024 + s)*3+2] = zs;
    }
    // fused distance update + next-iteration local argmax
    v2 xs2; xs2.x = xs; xs2.y = xs;
    v2 ys2; ys2.x = ys; ys2.y = ys;
    v2 zs2; zs2.x = zs; zs2.y = zs;
    bv = -2.0f; bi = 16383;
    #pragma unroll
    for (int r = 0; r < 16; r++){
      v2 dx = px[r] - xs2;
      v2 dy = py[r] - ys2;
      v2 dz = pz[r] - zs2;
      v2 qx = dx * dx;
      v2 qy = dy * dy;
      v2 qz = dz * dz;
      v2 s1 = qx + qy;
      v2 d  = s1 + qz;
      float m0 = fminf(mind[r].x, d.x);   // excluded rows stay -1 (d >= 0)
      float m1 = fminf(mind[r].y, d.y);
      mind[r].x = m0; mind[r].y = m1;
      if (m0 > bv){ bv = m0; bi = (2*r)*512 + t; }
      if (m1 > bv){ bv = m1; bi = (2*r+1)*512 + t; }
    }
  }
}

// ---------- ball query: one wave per query (inclusive <=, f32 radius^2) ----------
__global__ __launch_bounds__(256) void k_ball(const float* __restrict__ xyz, const float* __restrict__ newxyz,
                                              int* __restrict__ idxnb){
  int t = threadIdx.x; int lane = t & 63;
  int qid = blockIdx.x*4 + (t >> 6);
  int b = qid >> 10;
  const float* xb = xyz + (size_t)b * NPT * 3;
  float qx = newxyz[qid*3], qy = newxyz[qid*3+1], qz = newxyz[qid*3+2];
  int found = 0, first = -1;
  for (int base = 0; base < NPT; base += 64){
    int p = base + lane;
    float x = xb[p*3], y = xb[p*3+1], z = xb[p*3+2];
    float dx = __fsub_rn(qx, x), dy = __fsub_rn(qy, y), dz = __fsub_rn(qz, z);
    float d2 = __fadd_rn(__fadd_rn(__fmul_rn(dx,dx), __fmul_rn(dy,dy)), __fmul_rn(dz,dz));
    bool w = d2 <= 0.09f;
    u64 m = __ballot(w);
    if (first < 0 && m) first = base + __ffsll((unsigned long long)m) - 1;
    if (w){
      int pos = found + __popcll(m & ((1ull << lane) - 1ull));
      if (pos < NS) idxnb[(size_t)qid*NS + pos] = p;
    }
    found += __popcll(m);
    if (found >= NS) break;
  }
  if (first < 0) first = 0;   // defensive
  if (lane < NS && lane >= found) idxnb[(size_t)qid*NS + lane] = first;
}

// ---------- build grouped input X [131][P] bf16 ----------
__global__ __launch_bounds__(256) void k_buildX(const float* __restrict__ xyz, const float* __restrict__ newxyz,
                                                const int* __restrict__ idxnb, const float* __restrict__ feat,
                                                u16* __restrict__ Xb){
  int pos = blockIdx.x*256 + threadIdx.x;
  int b = pos >> 15; int r = pos & 32767; int s = r >> 5;
  int gi = idxnb[pos] & (NPT - 1);   // defensive clamp
  const float* xp = xyz + ((size_t)b*NPT + gi) * 3;
  const float* qp = newxyz + ((size_t)(b << 10) + s) * 3;
  #pragma unroll
  for (int c = 0; c < 3; c++) Xb[(size_t)c*PP + pos] = f2bf(__fsub_rn(xp[c], qp[c]));
  const float* fb = feat + (size_t)b*CIN*NPT + gi;
  for (int c = 0; c < CIN; c++) Xb[(size_t)(3+c)*PP + pos] = f2bf(fb[(size_t)c * NPT]);
}

// ---------- conv GEMM: Y[M][P] bf16 = Wt^T (fp32) x (affine?relu? X bf16), + stat partials ----------
template<int AFF, int STORE>
__global__ __launch_bounds__(256) void k_gemm_conv(const float* __restrict__ Wt, int Mtot,
                                                   const u16* __restrict__ Xin, int Kvalid, int nkc,
                                                   const float2* __restrict__ aff,
                                                   u16* __restrict__ Yout, double* __restrict__ cpart){
  __shared__ float As[32][64];
  __shared__ float Bs[32][64];
  int t = threadIdx.x, tx = t & 15, ty = t >> 4;
  int p0 = blockIdx.x * 64, m0 = blockIdx.y * 64;
  float acc[4][4] = {};
  int e = t * 8, ka = e >> 6, ca = e & 63;
  for (int kc = 0; kc < nkc; kc++){
    int kg = kc*32 + ka;
    const float* wr = Wt + (size_t)kg * Mtot + m0 + ca;
    float4 w0 = *(const float4*)wr;
    float4 w1v = *(const float4*)(wr + 4);
    float bv[8];
    if (kg < Kvalid){
      uint4 u = *(const uint4*)(Xin + (size_t)kg * PP + p0 + ca);
      u32 us[4] = {u.x, u.y, u.z, u.w};
      #pragma unroll
      for (int q = 0; q < 4; q++){ bv[2*q] = bf2f(us[q] & 0xFFFFu); bv[2*q+1] = bf2f(us[q] >> 16); }
      if (AFF){
        float2 af = aff[kg];
        #pragma unroll
        for (int q = 0; q < 8; q++) bv[q] = fmaxf(0.f, fmaf(bv[q], af.x, af.y));
      }
    } else {
      #pragma unroll
      for (int q = 0; q < 8; q++) bv[q] = 0.f;
    }
    __syncthreads();
    *(float4*)&As[ka][ca] = w0; *(float4*)&As[ka][ca+4] = w1v;
    #pragma unroll
    for (int q = 0; q < 8; q++) Bs[ka][ca+q] = bv[q];
    __syncthreads();
    #pragma unroll
    for (int k = 0; k < 32; k++){
      float4 a = *(float4*)&As[k][ty*4];
      float4 bq = *(float4*)&Bs[k][tx*4];
      float av[4] = {a.x,a.y,a.z,a.w}; float bw[4] = {bq.x,bq.y,bq.z,bq.w};
      #pragma unroll
      for (int i = 0; i < 4; i++)
        #pragma unroll
        for (int j = 0; j < 4; j++) acc[i][j] = fmaf(av[i], bw[j], acc[i][j]);
    }
  }
  if (STORE){
    #pragma unroll
    for (int i = 0; i < 4; i++){
      int m = m0 + ty*4 + i;
      ushort4 pk;
      pk.x = f2bf(acc[i][0]); pk.y = f2bf(acc[i][1]); pk.z = f2bf(acc[i][2]); pk.w = f2bf(acc[i][3]);
      *(ushort4*)(Yout + (size_t)m * PP + p0 + tx*4) = pk;
    }
  }
  __syncthreads();
  float* red = (float*)As;
  #pragma unroll
  for (int i = 0; i < 4; i++){
    float s = 0.f, q = 0.f;
    #pragma unroll
    for (int j = 0; j < 4; j++){ s += acc[i][j]; q += acc[i][j]*acc[i][j]; }
    red[((ty*4+i)*16 + tx)*2] = s; red[((ty*4+i)*16 + tx)*2 + 1] = q;
  }
  __syncthreads();
  if (t < 64){
    double s = 0.0, q = 0.0;
    for (int x = 0; x < 16; x++){ s += red[(t*16+x)*2]; q += red[(t*16+x)*2+1]; }
    cpart[((size_t)(m0 + t)*2048 + blockIdx.x)*2] = s;
    cpart[((size_t)(m0 + t)*2048 + blockIdx.x)*2 + 1] = q;
  }
}

__global__ __launch_bounds__(256) void k_stats_conv(const double* __restrict__ cpart,
                                                    const float* __restrict__ g, const float* __restrict__ bt,
                                                    float2* __restrict__ ssv){
  __shared__ double rs_[256], rq_[256];
  int ch = blockIdx.x, t = threadIdx.x;
  double s = 0.0, q = 0.0;
  for (int i = t; i < 2048; i += 256){ s += cpart[((size_t)ch*2048 + i)*2]; q += cpart[((size_t)ch*2048 + i)*2+1]; }
  rs_[t] = s; rq_[t] = q; __syncthreads();
  for (int off = 128; off; off >>= 1){
    if (t < off){ rs_[t] += rs_[t+off]; rq_[t] += rq_[t+off]; }
    __syncthreads();
  }
  if (t == 0){
    double cnt = (double)PP;
    double mu = rs_[0]/cnt; double var = rq_[0]/cnt - mu*mu;
    float rsf = 1.0f / sqrtf((float)var + 1e-5f);
    double rsd = (double)rsf;
    double gd = (double)g[ch]; double bd = (double)bt[ch];
    ssv[ch] = make_float2((float)(rsd*gd), (float)(bd - mu*rsd*gd));
  }
}

// ---------- fused layer-3 recompute + BN3 + relu + maxpool (one block per query) ----------
__global__ __launch_bounds__(256) void k_fuse3pool(const u16* __restrict__ Y2, const float* __restrict__ wt3,
                                                   const float2* __restrict__ ss1, const float2* __restrict__ ss2,
                                                   float* __restrict__ out1){
  __shared__ float Xs[128][32];
  int t = threadIdx.x;
  int q = blockIdx.x;            // b*1024 + s
  int b = q >> 10, s = q & 1023;
  size_t cb = (size_t)q << 5;    // column base in P
  #pragma unroll
  for (int e = 0; e < 16; e++){
    int idx = e*256 + t; int k = idx >> 5, j = idx & 31;
    float v = bf2f(Y2[(size_t)k*PP + cb + j]);
    float2 af = ss1[k];
    Xs[k][j] = fmaxf(0.f, fmaf(v, af.x, af.y));
  }
  __syncthreads();
  float acc[32] = {};
  for (int k = 0; k < 128; k++){
    float w = wt3[k*256 + t];
    const float4* xr = (const float4*)&Xs[k][0];
    #pragma unroll
    for (int jq = 0; jq < 8; jq++){
      float4 x = xr[jq];
      acc[jq*4+0] = fmaf(w, x.x, acc[jq*4+0]);
      acc[jq*4+1] = fmaf(w, x.y, acc[jq*4+1]);
      acc[jq*4+2] = fmaf(w, x.z, acc[jq*4+2]);
      acc[jq*4+3] = fmaf(w, x.w, acc[jq*4+3]);
    }
  }
  float2 a2 = ss2[t];
  float mx = 0.f;
  #pragma unroll
  for (int j = 0; j < 32; j++) mx = fmaxf(mx, fmaxf(0.f, fmaf(acc[j], a2.x, a2.y)));
  out1[((size_t)b << 18) + (size_t)t*1024 + s] = mx;
}

extern "C" void kernel_launch(void* const* d_in, const int* in_sizes, int n_in,
                              void* d_out, int out_size, void* d_ws, size_t ws_size,
                              hipStream_t stream){
  (void)in_sizes; (void)n_in; (void)out_size;
  if (ws_size < WS_NEED) return;
  const float* xyz    = (const float*)d_in[0];
  const float* feat   = (const float*)d_in[1];
  const float* w1     = (const float*)d_in[2];
  const float* g1     = (const float*)d_in[3];
  const float* b1     = (const float*)d_in[4];
  const float* w2     = (const float*)d_in[5];
  const float* g2     = (const float*)d_in[6];
  const float* b2     = (const float*)d_in[7];
  const float* w3     = (const float*)d_in[8];
  const float* g3     = (const float*)d_in[9];
  const float* b3     = (const float*)d_in[10];
  const float* fw1    = (const float*)d_in[11];
  const float* fg1    = (const float*)d_in[12];
  const float* fb1    = (const float*)d_in[13];
  const float* fw2    = (const float*)d_in[14];
  const float* fbias2 = (const float*)d_in[15];

  char* ws = (char*)d_ws;
  float*  newxyz = (float*)(ws + OFF_NEWXYZ);
  float*  margin = (float*)(ws + OFF_MARGIN);
  u32*    fgmask = (u32*)(ws + OFF_FGMASK);
  int*    idxnb  = (int*)(ws + OFF_IDXNB);
  float*  mstat  = (float*)(ws + OFF_MSTAT);
  float2* ss0    = (float2*)(ws + OFF_SSA);
  float2* ss1    = ss0 + 256;
  float2* ss2    = ss0 + 512;
  float*  wt0    = (float*)(ws + OFF_WT0);
  float*  wt1    = (float*)(ws + OFF_WT1);
  float*  wt2    = (float*)(ws + OFF_WT2);
  float*  wt3    = (float*)(ws + OFF_WT3);
  double* mpart  = (double*)(ws + OFF_MPART);
  double* cpart  = (double*)(ws + OFF_CPART);
  float*  y0     = (float*)(ws + OFF_REGB);   // 16 MB f32, dead after k_scores
  u16*    Y1     = (u16*)(ws + OFF_REGB);     // 32 MB bf16
  u16*    Xb     = (u16*)(ws + OFF_REGA);     // 34.3 MB bf16, dead after layer-1
  u16*    Y2     = (u16*)(ws + OFF_REGA);     // 32 MB bf16

  float* out  = (float*)d_out;
  float* out0 = out;            // [4,1024,3]
  float* out1 = out + 12288;    // [4,256,1024]
  float* out2 = out + 1060864;  // [4,1024]
  float* out3 = out + 1064960;  // [4,2,16384]

  k_prep<<<dim3(256), dim3(256), 0, stream>>>(w1, w2, w3, fw1, wt0, wt1, wt2, wt3);
  k_gemm_mask<<<dim3(256,1,4), dim3(256), 0, stream>>>(wt0, feat, y0, mpart);
  k_mask_stats<<<dim3(1), dim3(64), 0, stream>>>(mpart, mstat);
  k_scores<<<dim3(64,4), dim3(256), 0, stream>>>(y0, mstat, fg1, fb1, fw2, fbias2, margin, out3);
  k_topk<<<dim3(4), dim3(1024), 0, stream>>>(margin, fgmask);
  k_fps<<<dim3(8), dim3(512), 0, stream>>>(xyz, fgmask, newxyz, out0, out2);
  k_ball<<<dim3(1024), dim3(256), 0, stream>>>(xyz, newxyz, idxnb);
  k_buildX<<<dim3(512), dim3(256), 0, stream>>>(xyz, newxyz, idxnb, feat, Xb);
  k_gemm_conv<0,1><<<dim3(2048,2), dim3(256), 0, stream>>>(wt1, 128, Xb, 131, 5, nullptr, Y1, cpart);
  k_stats_conv<<<dim3(128), dim3(256), 0, stream>>>(cpart, g1, b1, ss0);
  k_gemm_conv<1,1><<<dim3(2048,2), dim3(256), 0, stream>>>(wt2, 128, Y1, 128, 4, ss0, Y2, cpart);
  k_stats_conv<<<dim3(128), dim3(256), 0, stream>>>(cpart, g2, b2, ss1);
  k_gemm_conv<1,0><<<dim3(2048,4), dim3(256), 0, stream>>>(wt3, 256, Y2, 128, 4, ss1, nullptr, cpart);
  k_stats_conv<<<dim3(256), dim3(256), 0, stream>>>(cpart, g3, b3, ss2);
  k_fuse3pool<<<dim3(4096), dim3(256), 0, stream>>>(Y2, wt3, ss1, ss2, out1);
}

// Round 7
// 1413.552 us; speedup vs baseline: 2.1671x; 2.1671x over previous
//
#include <hip/hip_runtime.h>

#define BB 4
#define NPT 16384
#define CIN 128
#define SS 1024
#define NS 32
#define PP 131072   // BB*SS*NS
#define TOPKK 2048

typedef unsigned short u16;
typedef unsigned int u32;
typedef unsigned long long u64;
typedef float v2 __attribute__((ext_vector_type(2)));

// ---------- helpers ----------
__device__ __forceinline__ float bf2f(u32 v){ return __uint_as_float(v << 16); }
__device__ __forceinline__ u16 f2bf(float f){
  u32 u = __float_as_uint(f);
  u32 r = (u + 0x7FFFu + ((u >> 16) & 1u)) >> 16;   // RNE
  return (u16)r;
}
__device__ __forceinline__ u32 keyOf(float m){
  u32 u = __float_as_uint(m);
  return (u & 0x80000000u) ? ~u : (u | 0x80000000u);  // monotone in float order
}

// ---------- ws layout (bytes) — total 78,748,160 (75.1 MB) ----------
#define OFF_NEWXYZ 0ull                 // B*S*3 f32        49152
#define OFF_MARGIN 49152ull             // B*N f32          262144
#define OFF_FGMASK 311296ull            // B*N u32          262144
#define OFF_IDXNB  573440ull            // B*S*NS i32       524288
#define OFF_MSTAT  1097728ull           // 64*2 f32         512
#define OFF_SSA    1098240ull           // 3*256 float2     6144
#define OFF_WT0    1104384ull           // 128*64 f32       32768
#define OFF_WT1    1137152ull           // 160*128 f32      81920
#define OFF_WT2    1219072ull           // 128*128 f32      65536
#define OFF_WT3    1284608ull           // 128*256 f32      131072
#define OFF_MPART  1415680ull           // 64*1024*2 f64    1048576
#define OFF_CPART  2464256ull           // 256*2048*2 f64   8388608
#define OFF_REGB   10852864ull          // y0 (16MB f32) then Y1 (32MB bf16); cx/cy/cz/cg overlap y0 after k_scores
#define OFF_REGA   44407296ull          // Xb (34.3MB bf16) then Y2 (32MB bf16)
#define WS_NEED    78748160ull

// ---------- prep: transposed/padded fp32 weights ----------
__global__ void k_prep(const float* __restrict__ w1, const float* __restrict__ w2,
                       const float* __restrict__ w3, const float* __restrict__ fw1,
                       float* __restrict__ wt0, float* __restrict__ wt1,
                       float* __restrict__ wt2, float* __restrict__ wt3){
  int gt = blockIdx.x*blockDim.x + threadIdx.x;
  int gs = gridDim.x*blockDim.x;
  for (int i = gt; i < 128*64;  i += gs){ int k=i>>6, m=i&63;  wt0[i] = fw1[m*128+k]; }
  for (int i = gt; i < 160*128; i += gs){ int k=i>>7, m=i&127; wt1[i] = (k<131)? w1[m*131+k] : 0.f; }
  for (int i = gt; i < 128*128; i += gs){ int k=i>>7, m=i&127; wt2[i] = w2[m*128+k]; }
  for (int i = gt; i < 128*256; i += gs){ int k=i>>8, m=i&255; wt3[i] = w3[m*128+k]; }
}

// ---------- mask-head GEMM: y0[b][64][N] = fw1 @ features, + deterministic stat partials ----------
__global__ __launch_bounds__(256) void k_gemm_mask(const float* __restrict__ Wt,    // [128][64]
                                                   const float* __restrict__ feat,  // [B][128][N] f32
                                                   float* __restrict__ y0,
                                                   double* __restrict__ mpart){     // [64][1024][2]
  __shared__ float As[32][64];
  __shared__ float Bs[32][64];
  int t = threadIdx.x, tx = t & 15, ty = t >> 4;
  int p0 = blockIdx.x * 64; int b = blockIdx.z;
  const float* X = feat + (size_t)b * CIN * NPT;
  float acc[4][4] = {};
  int e = t * 8, ka = e >> 6, ca = e & 63;
  for (int kc = 0; kc < 4; kc++){
    const float* wr = Wt + (size_t)(kc*32 + ka) * 64 + ca;
    float4 w0 = *(const float4*)wr;
    float4 w1v = *(const float4*)(wr + 4);
    const float* br = X + (size_t)(kc*32 + ka) * NPT + p0 + ca;
    float4 b0 = *(const float4*)br;
    float4 b1 = *(const float4*)(br + 4);
    __syncthreads();
    *(float4*)&As[ka][ca] = w0; *(float4*)&As[ka][ca+4] = w1v;
    *(float4*)&Bs[ka][ca] = b0; *(float4*)&Bs[ka][ca+4] = b1;
    __syncthreads();
    #pragma unroll
    for (int k = 0; k < 32; k++){
      float4 a = *(float4*)&As[k][ty*4];
      float4 bq = *(float4*)&Bs[k][tx*4];
      float av[4] = {a.x,a.y,a.z,a.w}; float bw[4] = {bq.x,bq.y,bq.z,bq.w};
      #pragma unroll
      for (int i = 0; i < 4; i++)
        #pragma unroll
        for (int j = 0; j < 4; j++) acc[i][j] = fmaf(av[i], bw[j], acc[i][j]);
    }
  }
  #pragma unroll
  for (int i = 0; i < 4; i++){
    int m = ty*4 + i;
    float4 v = make_float4(acc[i][0], acc[i][1], acc[i][2], acc[i][3]);
    *(float4*)(y0 + ((size_t)(b*64 + m)) * NPT + p0 + tx*4) = v;
  }
  __syncthreads();
  float* red = (float*)As;  // 2048 floats
  #pragma unroll
  for (int i = 0; i < 4; i++){
    float s = 0.f, q = 0.f;
    #pragma unroll
    for (int j = 0; j < 4; j++){ s += acc[i][j]; q += acc[i][j]*acc[i][j]; }
    red[((ty*4+i)*16 + tx)*2] = s; red[((ty*4+i)*16 + tx)*2 + 1] = q;
  }
  __syncthreads();
  if (t < 64){
    double s = 0.0, q = 0.0;
    for (int x = 0; x < 16; x++){ s += red[(t*16+x)*2]; q += red[(t*16+x)*2+1]; }
    int slot = b*256 + blockIdx.x;
    mpart[((size_t)t*1024 + slot)*2] = s;
    mpart[((size_t)t*1024 + slot)*2 + 1] = q;
  }
}

__global__ void k_mask_stats(const double* __restrict__ mpart, float* __restrict__ mstat){ // <<<1,64>>>
  int t = threadIdx.x;
  double s = 0.0, q = 0.0;
  for (int i = 0; i < 1024; i++){ s += mpart[((size_t)t*1024 + i)*2]; q += mpart[((size_t)t*1024 + i)*2+1]; }
  double cnt = 65536.0;
  double mu = s/cnt; double var = q/cnt - mu*mu;
  float muf = (float)mu;
  float rs = 1.0f / sqrtf((float)var + 1e-5f);
  mstat[t*2] = muf; mstat[t*2+1] = rs;
}

// ---------- scores + margin ----------
__global__ __launch_bounds__(256) void k_scores(const float* __restrict__ y0, const float* __restrict__ mstat,
                                                const float* __restrict__ fg1, const float* __restrict__ fb1,
                                                const float* __restrict__ fw2, const float* __restrict__ fbias2,
                                                float* __restrict__ margin, float* __restrict__ out3){
  __shared__ float smu[64], srs[64], sg[64], sb[64], sw[128];
  int t = threadIdx.x; int b = blockIdx.y; int n = blockIdx.x*256 + t;
  if (t < 64){ smu[t] = mstat[t*2]; srs[t] = mstat[t*2+1]; sg[t] = fg1[t]; sb[t] = fb1[t]; }
  if (t < 128) sw[t] = fw2[t];
  __syncthreads();
  float a0 = 0.f, a1 = 0.f;
  const float* yb = y0 + (size_t)b*64*NPT + n;
  for (int o = 0; o < 64; o++){
    float y = yb[(size_t)o * NPT];
    float h = __fmul_rn(__fmul_rn(__fsub_rn(y, smu[o]), srs[o]), sg[o]);
    h = __fadd_rn(h, sb[o]);
    h = fmaxf(h, 0.f);
    a0 = fmaf(sw[o], h, a0);
    a1 = fmaf(sw[64+o], h, a1);
  }
  float s0 = __fadd_rn(a0, fbias2[0]);
  float s1 = __fadd_rn(a1, fbias2[1]);
  out3[(size_t)(b*2)*NPT + n] = s0;
  out3[(size_t)(b*2+1)*NPT + n] = s1;
  float m = fmaxf(s0, s1);
  float e0 = expf(__fsub_rn(s0, m));
  float e1 = expf(__fsub_rn(s1, m));
  float den = __fadd_rn(e0, e1);
  float mg = __fsub_rn(__fdiv_rn(e1, den), __fdiv_rn(e0, den));
  margin[b*NPT + n] = mg;
}

// ---------- top-2048 per batch -> fg mask (radix select + stable index tie-break) ----------
__global__ __launch_bounds__(1024) void k_topk(const float* __restrict__ margin, u32* __restrict__ fgmask){
  int t = threadIdx.x; int b = blockIdx.x;
  const float* mg = margin + b*NPT; u32* fm = fgmask + b*NPT;
  __shared__ int hist[256]; __shared__ int sc[1024];
  __shared__ u32 s_bin; __shared__ int s_need; __shared__ int s_run;
  int need = TOPKK; u32 prefix = 0, kmask = 0;
  for (int r = 0; r < 4; r++){
    int shift = 24 - 8*r;
    if (t < 256) hist[t] = 0;
    __syncthreads();
    for (int j = 0; j < 16; j++){
      u32 key = keyOf(mg[j*1024 + t]);
      if ((key & kmask) == prefix) atomicAdd(&hist[(key >> shift) & 255], 1);
    }
    __syncthreads();
    if (t == 0){
      int cum = 0;
      for (int bin = 255; bin >= 0; bin--){
        int c = hist[bin];
        if (cum + c >= need){ s_bin = (u32)bin; s_need = need - cum; break; }
        cum += c;
      }
    }
    __syncthreads();
    prefix |= s_bin << shift; kmask |= 255u << shift; need = s_need;
    __syncthreads();
  }
  u32 T = prefix;
  if (t == 0) s_run = 0;
  __syncthreads();
  for (int j = 0; j < 16; j++){
    int n = j*1024 + t;
    u32 key = keyOf(mg[n]);
    int eq = (key == T) ? 1 : 0;
    int gt = (key > T) ? 1 : 0;
    sc[t] = eq; __syncthreads();
    for (int off = 1; off < 1024; off <<= 1){
      int v = (t >= off) ? sc[t-off] : 0;
      __syncthreads();
      sc[t] += v;
      __syncthreads();
    }
    int excl = sc[t] - eq;
    int flag = gt | (eq & ((s_run + excl) < need ? 1 : 0));
    fm[n] = (u32)flag;
    __syncthreads();
    if (t == 1023) s_run += sc[1023];
    __syncthreads();
  }
}

// ---------- compact masked candidates (stable, ascending index) ----------
// 8 blocks: (b, which). fg -> 2048 entries at seg base b*16384; bg -> 14336 at +2048.
__global__ __launch_bounds__(1024) void k_compact(const float* __restrict__ xyz, const u32* __restrict__ fgmask,
                                                  float* __restrict__ cx, float* __restrict__ cy,
                                                  float* __restrict__ cz, int* __restrict__ cg){
  int blk = blockIdx.x; int b = blk >> 1; int which = blk & 1;
  const float* xb = xyz + (size_t)b * NPT * 3;
  const u32* mb = fgmask + b*NPT;
  int t = threadIdx.x;
  __shared__ int sc[1024];
  u32 mloc = 0; int cnt = 0;
  int p0 = t*16;
  #pragma unroll
  for (int j = 0; j < 16; j++){
    u32 m = mb[p0+j];
    bool inc = which ? (m == 0u) : (m != 0u);
    mloc |= (inc ? 1u : 0u) << j; cnt += inc ? 1 : 0;
  }
  sc[t] = cnt; __syncthreads();
  for (int off = 1; off < 1024; off <<= 1){
    int v = (t >= off) ? sc[t-off] : 0;
    __syncthreads();
    sc[t] += v;
    __syncthreads();
  }
  int pos = sc[t] - cnt;
  int base = b*16384 + (which ? 2048 : 0);
  for (int j = 0; j < 16; j++){
    if ((mloc >> j) & 1u){
      int p = p0 + j;
      cx[base+pos] = xb[p*3]; cy[base+pos] = xb[p*3+1]; cz[base+pos] = xb[p*3+2];
      cg[base+pos] = p; pos++;
    }
  }
}

// ---------- masked FPS on compacted candidates ----------
// Reduction: per-lane atomicMax(u64) spread over 8 LDS slots (lane&7) -> barrier ->
// 8-slot read + in-register max. Key = (it+1)<<46 | keyOf(v)<<14 | (16383-idx):
// iteration prefix makes stale entries lose (no resets); low field gives exact
// lowest-index tie-break (compaction preserves ascending order).
template<int NV>   // v2-rows per thread; candidates = NV*1024 (512 threads)
__device__ __forceinline__ void fps_run(const float* __restrict__ cx, const float* __restrict__ cy,
                                        const float* __restrict__ cz, const int* __restrict__ cg,
                                        int b, int which,
                                        float* __restrict__ newxyz, float* __restrict__ out0,
                                        float* __restrict__ out2){
  #pragma clang fp contract(off)
  int t = threadIdx.x;
  __shared__ u64 slots[2][8];
  if (t < 16) ((u64*)slots)[t] = 0ull;
  v2 px[NV], py[NV], pz[NV], mind[NV];
  #pragma unroll
  for (int r = 0; r < NV; r++){
    int p0 = 1024*r + t, p1 = 1024*r + 512 + t;
    px[r].x = cx[p0]; px[r].y = cx[p1];
    py[r].x = cy[p0]; py[r].y = cy[p1];
    pz[r].x = cz[p0]; pz[r].y = cz[p1];
    mind[r].x = 1e10f; mind[r].y = 1e10f;
  }
  __syncthreads();
  float bv = 1e10f; int bi = t;   // all equal -> lowest local index
  for (int it = 0; it < 512; it++){
    u64 key = ((u64)(it+1) << 46) | ((u64)keyOf(bv) << 14) | (u64)(16383 - bi);
    atomicMax((unsigned long long*)&slots[it & 1][t & 7], (unsigned long long)key);
    __syncthreads();
    u64 k0 = slots[it & 1][0];
    #pragma unroll
    for (int i = 1; i < 8; i++){ u64 ki = slots[it & 1][i]; if (ki > k0) k0 = ki; }
    int sel = 16383 - (int)(k0 & 0x3FFFu);
    float xs = cx[sel], ys = cy[sel], zs = cz[sel];   // uniform L2-resident load
    if (t == 0){
      int s = which*512 + it;
      out2[b*1024 + s] = (float)cg[sel];
      newxyz[(b*1024 + s)*3]   = xs;
      newxyz[(b*1024 + s)*3+1] = ys;
      newxyz[(b*1024 + s)*3+2] = zs;
      out0[(b*1024 + s)*3]   = xs;
      out0[(b*1024 + s)*3+1] = ys;
      out0[(b*1024 + s)*3+2] = zs;
    }
    v2 xs2; xs2.x = xs; xs2.y = xs;
    v2 ys2; ys2.x = ys; ys2.y = ys;
    v2 zs2; zs2.x = zs; zs2.y = zs;
    bv = -1.0f; bi = 16383;
    #pragma unroll
    for (int r = 0; r < NV; r++){
      v2 dx = px[r] - xs2;
      v2 dy = py[r] - ys2;
      v2 dz = pz[r] - zs2;
      v2 qx = dx * dx;
      v2 qy = dy * dy;
      v2 qz = dz * dz;
      v2 s1 = qx + qy;
      v2 d  = s1 + qz;
      float m0 = fminf(mind[r].x, d.x);
      float m1 = fminf(mind[r].y, d.y);
      mind[r].x = m0; mind[r].y = m1;
      if (m0 > bv){ bv = m0; bi = 1024*r + t; }
      if (m1 > bv){ bv = m1; bi = 1024*r + 512 + t; }
    }
  }
}

__global__ __launch_bounds__(512) void k_fps(const float* __restrict__ cx, const float* __restrict__ cy,
                                             const float* __restrict__ cz, const int* __restrict__ cg,
                                             float* __restrict__ newxyz, float* __restrict__ out0,
                                             float* __restrict__ out2){
  int b = blockIdx.x >> 1; int which = blockIdx.x & 1;
  int base = b*16384 + (which ? 2048 : 0);
  if (which) fps_run<14>(cx+base, cy+base, cz+base, cg+base, b, 1, newxyz, out0, out2);
  else       fps_run<2 >(cx+base, cy+base, cz+base, cg+base, b, 0, newxyz, out0, out2);
}

// ---------- ball query: one wave per query (inclusive <=, f32 radius^2) ----------
__global__ __launch_bounds__(256) void k_ball(const float* __restrict__ xyz, const float* __restrict__ newxyz,
                                              int* __restrict__ idxnb){
  int t = threadIdx.x; int lane = t & 63;
  int qid = blockIdx.x*4 + (t >> 6);
  int b = qid >> 10;
  const float* xb = xyz + (size_t)b * NPT * 3;
  float qx = newxyz[qid*3], qy = newxyz[qid*3+1], qz = newxyz[qid*3+2];
  int found = 0, first = -1;
  for (int base = 0; base < NPT; base += 64){
    int p = base + lane;
    float x = xb[p*3], y = xb[p*3+1], z = xb[p*3+2];
    float dx = __fsub_rn(qx, x), dy = __fsub_rn(qy, y), dz = __fsub_rn(qz, z);
    float d2 = __fadd_rn(__fadd_rn(__fmul_rn(dx,dx), __fmul_rn(dy,dy)), __fmul_rn(dz,dz));
    bool w = d2 <= 0.09f;
    u64 m = __ballot(w);
    if (first < 0 && m) first = base + __ffsll((unsigned long long)m) - 1;
    if (w){
      int pos = found + __popcll(m & ((1ull << lane) - 1ull));
      if (pos < NS) idxnb[(size_t)qid*NS + pos] = p;
    }
    found += __popcll(m);
    if (found >= NS) break;
  }
  if (first < 0) first = 0;   // defensive
  if (lane < NS && lane >= found) idxnb[(size_t)qid*NS + lane] = first;
}

// ---------- build grouped input X [131][P] bf16 ----------
__global__ __launch_bounds__(256) void k_buildX(const float* __restrict__ xyz, const float* __restrict__ newxyz,
                                                const int* __restrict__ idxnb, const float* __restrict__ feat,
                                                u16* __restrict__ Xb){
  int pos = blockIdx.x*256 + threadIdx.x;
  int b = pos >> 15; int r = pos & 32767; int s = r >> 5;
  int gi = idxnb[pos] & (NPT - 1);   // defensive clamp
  const float* xp = xyz + ((size_t)b*NPT + gi) * 3;
  const float* qp = newxyz + ((size_t)(b << 10) + s) * 3;
  #pragma unroll
  for (int c = 0; c < 3; c++) Xb[(size_t)c*PP + pos] = f2bf(__fsub_rn(xp[c], qp[c]));
  const float* fb = feat + (size_t)b*CIN*NPT + gi;
  for (int c = 0; c < CIN; c++) Xb[(size_t)(3+c)*PP + pos] = f2bf(fb[(size_t)c * NPT]);
}

// ---------- conv GEMM: Y[M][P] bf16 = Wt^T (fp32) x (affine?relu? X bf16), + stat partials ----------
template<int AFF, int STORE>
__global__ __launch_bounds__(256) void k_gemm_conv(const float* __restrict__ Wt, int Mtot,
                                                   const u16* __restrict__ Xin, int Kvalid, int nkc,
                                                   const float2* __restrict__ aff,
                                                   u16* __restrict__ Yout, double* __restrict__ cpart){
  __shared__ float As[32][64];
  __shared__ float Bs[32][64];
  int t = threadIdx.x, tx = t & 15, ty = t >> 4;
  int p0 = blockIdx.x * 64, m0 = blockIdx.y * 64;
  float acc[4][4] = {};
  int e = t * 8, ka = e >> 6, ca = e & 63;
  for (int kc = 0; kc < nkc; kc++){
    int kg = kc*32 + ka;
    const float* wr = Wt + (size_t)kg * Mtot + m0 + ca;
    float4 w0 = *(const float4*)wr;
    float4 w1v = *(const float4*)(wr + 4);
    float bv[8];
    if (kg < Kvalid){
      uint4 u = *(const uint4*)(Xin + (size_t)kg * PP + p0 + ca);
      u32 us[4] = {u.x, u.y, u.z, u.w};
      #pragma unroll
      for (int q = 0; q < 4; q++){ bv[2*q] = bf2f(us[q] & 0xFFFFu); bv[2*q+1] = bf2f(us[q] >> 16); }
      if (AFF){
        float2 af = aff[kg];
        #pragma unroll
        for (int q = 0; q < 8; q++) bv[q] = fmaxf(0.f, fmaf(bv[q], af.x, af.y));
      }
    } else {
      #pragma unroll
      for (int q = 0; q < 8; q++) bv[q] = 0.f;
    }
    __syncthreads();
    *(float4*)&As[ka][ca] = w0; *(float4*)&As[ka][ca+4] = w1v;
    #pragma unroll
    for (int q = 0; q < 8; q++) Bs[ka][ca+q] = bv[q];
    __syncthreads();
    #pragma unroll
    for (int k = 0; k < 32; k++){
      float4 a = *(float4*)&As[k][ty*4];
      float4 bq = *(float4*)&Bs[k][tx*4];
      float av[4] = {a.x,a.y,a.z,a.w}; float bw[4] = {bq.x,bq.y,bq.z,bq.w};
      #pragma unroll
      for (int i = 0; i < 4; i++)
        #pragma unroll
        for (int j = 0; j < 4; j++) acc[i][j] = fmaf(av[i], bw[j], acc[i][j]);
    }
  }
  if (STORE){
    #pragma unroll
    for (int i = 0; i < 4; i++){
      int m = m0 + ty*4 + i;
      ushort4 pk;
      pk.x = f2bf(acc[i][0]); pk.y = f2bf(acc[i][1]); pk.z = f2bf(acc[i][2]); pk.w = f2bf(acc[i][3]);
      *(ushort4*)(Yout + (size_t)m * PP + p0 + tx*4) = pk;
    }
  }
  __syncthreads();
  float* red = (float*)As;
  #pragma unroll
  for (int i = 0; i < 4; i++){
    float s = 0.f, q = 0.f;
    #pragma unroll
    for (int j = 0; j < 4; j++){ s += acc[i][j]; q += acc[i][j]*acc[i][j]; }
    red[((ty*4+i)*16 + tx)*2] = s; red[((ty*4+i)*16 + tx)*2 + 1] = q;
  }
  __syncthreads();
  if (t < 64){
    double s = 0.0, q = 0.0;
    for (int x = 0; x < 16; x++){ s += red[(t*16+x)*2]; q += red[(t*16+x)*2+1]; }
    cpart[((size_t)(m0 + t)*2048 + blockIdx.x)*2] = s;
    cpart[((size_t)(m0 + t)*2048 + blockIdx.x)*2 + 1] = q;
  }
}

__global__ __launch_bounds__(256) void k_stats_conv(const double* __restrict__ cpart,
                                                    const float* __restrict__ g, const float* __restrict__ bt,
                                                    float2* __restrict__ ssv){
  __shared__ double rs_[256], rq_[256];
  int ch = blockIdx.x, t = threadIdx.x;
  double s = 0.0, q = 0.0;
  for (int i = t; i < 2048; i += 256){ s += cpart[((size_t)ch*2048 + i)*2]; q += cpart[((size_t)ch*2048 + i)*2+1]; }
  rs_[t] = s; rq_[t] = q; __syncthreads();
  for (int off = 128; off; off >>= 1){
    if (t < off){ rs_[t] += rs_[t+off]; rq_[t] += rq_[t+off]; }
    __syncthreads();
  }
  if (t == 0){
    double cnt = (double)PP;
    double mu = rs_[0]/cnt; double var = rq_[0]/cnt - mu*mu;
    float rsf = 1.0f / sqrtf((float)var + 1e-5f);
    double rsd = (double)rsf;
    double gd = (double)g[ch]; double bd = (double)bt[ch];
    ssv[ch] = make_float2((float)(rsd*gd), (float)(bd - mu*rsd*gd));
  }
}

// ---------- fused layer-3 recompute + BN3 + relu + maxpool (one block per query) ----------
__global__ __launch_bounds__(256) void k_fuse3pool(const u16* __restrict__ Y2, const float* __restrict__ wt3,
                                                   const float2* __restrict__ ss1, const float2* __restrict__ ss2,
                                                   float* __restrict__ out1){
  __shared__ float Xs[128][32];
  int t = threadIdx.x;
  int q = blockIdx.x;            // b*1024 + s
  int b = q >> 10, s = q & 1023;
  size_t cb = (size_t)q << 5;    // column base in P
  #pragma unroll
  for (int e = 0; e < 16; e++){
    int idx = e*256 + t; int k = idx >> 5, j = idx & 31;
    float v = bf2f(Y2[(size_t)k*PP + cb + j]);
    float2 af = ss1[k];
    Xs[k][j] = fmaxf(0.f, fmaf(v, af.x, af.y));
  }
  __syncthreads();
  float acc[32] = {};
  for (int k = 0; k < 128; k++){
    float w = wt3[k*256 + t];
    const float4* xr = (const float4*)&Xs[k][0];
    #pragma unroll
    for (int jq = 0; jq < 8; jq++){
      float4 x = xr[jq];
      acc[jq*4+0] = fmaf(w, x.x, acc[jq*4+0]);
      acc[jq*4+1] = fmaf(w, x.y, acc[jq*4+1]);
      acc[jq*4+2] = fmaf(w, x.z, acc[jq*4+2]);
      acc[jq*4+3] = fmaf(w, x.w, acc[jq*4+3]);
    }
  }
  float2 a2 = ss2[t];
  float mx = 0.f;
  #pragma unroll
  for (int j = 0; j < 32; j++) mx = fmaxf(mx, fmaxf(0.f, fmaf(acc[j], a2.x, a2.y)));
  out1[((size_t)b << 18) + (size_t)t*1024 + s] = mx;
}

extern "C" void kernel_launch(void* const* d_in, const int* in_sizes, int n_in,
                              void* d_out, int out_size, void* d_ws, size_t ws_size,
                              hipStream_t stream){
  (void)in_sizes; (void)n_in; (void)out_size;
  if (ws_size < WS_NEED) return;
  const float* xyz    = (const float*)d_in[0];
  const float* feat   = (const float*)d_in[1];
  const float* w1     = (const float*)d_in[2];
  const float* g1     = (const float*)d_in[3];
  const float* b1     = (const float*)d_in[4];
  const float* w2     = (const float*)d_in[5];
  const float* g2     = (const float*)d_in[6];
  const float* b2     = (const float*)d_in[7];
  const float* w3     = (const float*)d_in[8];
  const float* g3     = (const float*)d_in[9];
  const float* b3     = (const float*)d_in[10];
  const float* fw1    = (const float*)d_in[11];
  const float* fg1    = (const float*)d_in[12];
  const float* fb1    = (const float*)d_in[13];
  const float* fw2    = (const float*)d_in[14];
  const float* fbias2 = (const float*)d_in[15];

  char* ws = (char*)d_ws;
  float*  newxyz = (float*)(ws + OFF_NEWXYZ);
  float*  margin = (float*)(ws + OFF_MARGIN);
  u32*    fgmask = (u32*)(ws + OFF_FGMASK);
  int*    idxnb  = (int*)(ws + OFF_IDXNB);
  float*  mstat  = (float*)(ws + OFF_MSTAT);
  float2* ss0    = (float2*)(ws + OFF_SSA);
  float2* ss1    = ss0 + 256;
  float2* ss2    = ss0 + 512;
  float*  wt0    = (float*)(ws + OFF_WT0);
  float*  wt1    = (float*)(ws + OFF_WT1);
  float*  wt2    = (float*)(ws + OFF_WT2);
  float*  wt3    = (float*)(ws + OFF_WT3);
  double* mpart  = (double*)(ws + OFF_MPART);
  double* cpart  = (double*)(ws + OFF_CPART);
  float*  y0     = (float*)(ws + OFF_REGB);   // 16 MB f32, dead after k_scores
  u16*    Y1     = (u16*)(ws + OFF_REGB);     // 32 MB bf16 (written at layer-1, after k_fps done)
  u16*    Xb     = (u16*)(ws + OFF_REGA);     // 34.3 MB bf16, dead after layer-1
  u16*    Y2     = (u16*)(ws + OFF_REGA);     // 32 MB bf16
  // compact candidate arrays overlap dead y0 (written by k_compact after k_scores,
  // read by k_fps, dead before layer-1 writes Y1 in the same region)
  float*  cx     = (float*)(ws + OFF_REGB);
  float*  cy     = cx + 4*16384;
  float*  cz     = cy + 4*16384;
  int*    cg     = (int*)(cz + 4*16384);

  float* out  = (float*)d_out;
  float* out0 = out;            // [4,1024,3]
  float* out1 = out + 12288;    // [4,256,1024]
  float* out2 = out + 1060864;  // [4,1024]
  float* out3 = out + 1064960;  // [4,2,16384]

  k_prep<<<dim3(256), dim3(256), 0, stream>>>(w1, w2, w3, fw1, wt0, wt1, wt2, wt3);
  k_gemm_mask<<<dim3(256,1,4), dim3(256), 0, stream>>>(wt0, feat, y0, mpart);
  k_mask_stats<<<dim3(1), dim3(64), 0, stream>>>(mpart, mstat);
  k_scores<<<dim3(64,4), dim3(256), 0, stream>>>(y0, mstat, fg1, fb1, fw2, fbias2, margin, out3);
  k_topk<<<dim3(4), dim3(1024), 0, stream>>>(margin, fgmask);
  k_compact<<<dim3(8), dim3(1024), 0, stream>>>(xyz, fgmask, cx, cy, cz, cg);
  k_fps<<<dim3(8), dim3(512), 0, stream>>>(cx, cy, cz, cg, newxyz, out0, out2);
  k_ball<<<dim3(1024), dim3(256), 0, stream>>>(xyz, newxyz, idxnb);
  k_buildX<<<dim3(512), dim3(256), 0, stream>>>(xyz, newxyz, idxnb, feat, Xb);
  k_gemm_conv<0,1><<<dim3(2048,2), dim3(256), 0, stream>>>(wt1, 128, Xb, 131, 5, nullptr, Y1, cpart);
  k_stats_conv<<<dim3(128), dim3(256), 0, stream>>>(cpart, g1, b1, ss0);
  k_gemm_conv<1,1><<<dim3(2048,2), dim3(256), 0, stream>>>(wt2, 128, Y1, 128, 4, ss0, Y2, cpart);
  k_stats_conv<<<dim3(128), dim3(256), 0, stream>>>(cpart, g2, b2, ss1);
  k_gemm_conv<1,0><<<dim3(2048,4), dim3(256), 0, stream>>>(wt3, 256, Y2, 128, 4, ss1, nullptr, cpart);
  k_stats_conv<<<dim3(256), dim3(256), 0, stream>>>(cpart, g3, b3, ss2);
  k_fuse3pool<<<dim3(4096), dim3(256), 0, stream>>>(Y2, wt3, ss1, ss2, out1);
}